// Round 8
// baseline (616.329 us; speedup 1.0000x reference)
//
#include <hip/hip_runtime.h>
#include <hip/hip_fp16.h>

// Bidirectional char-LSTM + masked max-pool via MFMA, 16-wave split-phase.
// 32 blocks = 2 dirs x 16 chain-groups; block runs 16 chains (shared weights),
// T=512 steps. Per step: D[16][512] = A[16][192] x B[192][512] via
// mfma_f32_16x16x32_f16, weights in VGPRs (12 f16x8 frags/wave).
// 16 waves: wave w<8 owns gate cols {w*16 (i), +256 (g)}; wave w+8 owns
// {+128 (f), +384 (o)} for the same 16 hidden dims. Activation split:
// waves 8-15 compute sigma(f),sigma(o) -> LDS (pad-17, conflict-free);
// waves 0-7 compute sigma(i),tanh(g), then after barrier A the c/h update
// (trans critical depth 40 -> 24) and h-write; waves 8-15 write the x
// prefetch. R7 lesson: 2 waves/SIMD left the serial
// ds_read->MFMA->trans->barrier chain exposed (2750cyc/step vs ~1100 issue);
// 4 waves/SIMD + split phases attack the stall.

#define TT 512
#define CH 16      // chains per block
#define ROWB 384   // bytes per A row (192 halves)

typedef _Float16 f16;
typedef _Float16 f16x8 __attribute__((ext_vector_type(8)));
typedef float f32x4 __attribute__((ext_vector_type(4)));
typedef unsigned int u32;
typedef unsigned short u16;

static __device__ __forceinline__ u32 packh2(float lo, float hi) {
    union { struct { f16 x, y; } h; u32 u; } cv;
    cv.h.x = (f16)lo; cv.h.y = (f16)hi;
    return cv.u;
}
static __device__ __forceinline__ u16 f16bits(float v) {
    union { f16 h; u16 u; } cv; cv.h = (f16)v; return cv.u;
}
static __device__ __forceinline__ float fexp(float x) {
    return __builtin_amdgcn_exp2f(x * 1.44269504088896341f);
}
static __device__ __forceinline__ float frcp(float x) {
    return __builtin_amdgcn_rcpf(x);
}
static __device__ __forceinline__ float sigf(float x) {
    return frcp(1.f + fexp(-x));
}
static __device__ __forceinline__ float tanhf_(float x) {
    return 1.f - 2.f * frcp(fexp(2.f * x) + 1.f);
}

__global__ __attribute__((amdgpu_flat_work_group_size(1024, 1024),
                          amdgpu_num_vgpr(128)))
void bilstm_mfma16_kernel(const int* __restrict__ idx,
                          const float* __restrict__ masks,
                          const float* __restrict__ emb,
                          const float* __restrict__ Wih_f, const float* __restrict__ Whh_f,
                          const float* __restrict__ bih_f, const float* __restrict__ bhh_f,
                          const float* __restrict__ Wih_b, const float* __restrict__ Whh_b,
                          const float* __restrict__ bih_b, const float* __restrict__ bhh_b,
                          float* __restrict__ out)
{
    __shared__ __align__(16) unsigned char Abuf[2][CH * ROWB]; // 12 KB
    __shared__ u16 idx16[CH * TT];                             // 16 KB
    __shared__ u32 mbits[TT];                                  // 2 KB
    __shared__ float sf_l[128 * 17];                           // 8.5 KB
    __shared__ float so_l[128 * 17];                           // 8.5 KB

    const int tid  = threadIdx.x;
    const int lane = tid & 63;
    const int wv   = tid >> 6;        // wave 0..15
    const int gg   = wv & 7;          // hidden-dim group 0..7
    const int hf   = wv >> 3;         // 0: i/g + activator; 1: f/o + prefetch
    const int l15  = lane & 15;
    const int c4   = lane >> 4;       // 0..3 (chain group)
    const int d    = blockIdx.x >> 4; // 0 fwd, 1 bwd
    const int g    = blockIdx.x & 15;
    const int b0   = g * CH;
    const int rev  = d;

    const float* Wih = d ? Wih_b : Wih_f;
    const float* Whh = d ? Whh_b : Whh_f;
    const float* bih = d ? bih_b : bih_f;
    const float* bhh = d ? bhh_b : bhh_f;

    // ---- init: idx (u16), mask bitmasks, zero A buffers
    for (int i = tid; i < CH * TT; i += 1024) {
        const int m = i >> 9, t = i & 511;
        idx16[i] = (u16)idx[(b0 + m) * TT + t];
    }
    if (tid < TT) {
        u32 mb = 0;
        for (int m = 0; m < CH; ++m)
            mb |= (masks[(b0 + m) * TT + tid] != 0.f ? 1u : 0u) << m;
        mbits[tid] = mb;
    }
    for (int i = tid; i < 2 * CH * ROWB / 4; i += 1024)
        ((u32*)Abuf)[i] = 0u;

    // ---- B fragments: wave owns cols n0 = hf*128+gg*16+l15 and n0+256.
    // Lane holds B[kt*32 + c4*8 + j][n], j=0..7.
    const int ncol0 = hf * 128 + gg * 16 + l15;
    f16x8 w[6][2];
    float bias_v[2];
#pragma unroll
    for (int nt = 0; nt < 2; ++nt) {
        const int n = ncol0 + nt * 256;
        bias_v[nt] = bih[n] + bhh[n];
        // kt = 0: k = c4*8 + j (< 32 < 50) -> Wih
#pragma unroll
        for (int jj = 0; jj < 4; ++jj) {
            const float2 e = *(const float2*)(Wih + n * 50 + c4 * 8 + jj * 2);
            w[0][nt][2 * jj]     = (f16)e.x;
            w[0][nt][2 * jj + 1] = (f16)e.y;
        }
        // kt = 1: k = 32 + c4*8 + j, real iff k < 50
#pragma unroll
        for (int j = 0; j < 8; ++j) {
            const int k = 32 + c4 * 8 + j;
            float v = 0.f;
            if (k < 50) v = Wih[n * 50 + k];
            w[1][nt][j] = (f16)v;
        }
        // kt = 2..5: k >= 64 -> Whh
#pragma unroll
        for (int kt = 2; kt < 6; ++kt) {
            const int kh = (kt - 2) * 32 + c4 * 8;
            const float4 e0 = *(const float4*)(Whh + n * 128 + kh);
            const float4 e1 = *(const float4*)(Whh + n * 128 + kh + 4);
            w[kt][nt][0] = (f16)e0.x; w[kt][nt][1] = (f16)e0.y;
            w[kt][nt][2] = (f16)e0.z; w[kt][nt][3] = (f16)e0.w;
            w[kt][nt][4] = (f16)e1.x; w[kt][nt][5] = (f16)e1.y;
            w[kt][nt][6] = (f16)e1.z; w[kt][nt][7] = (f16)e1.w;
        }
    }

    __syncthreads();   // idx16/mbits/Abuf-zero visible (R7 had a latent race)

    // ---- x for step 0: threads 0..399, 25 per chain, 2 halves each
    if (tid < 400) {
        const int pm = tid / 25, ps = tid % 25;
        const int t0  = rev ? (TT - 1) : 0;
        const int row = idx16[pm * TT + t0];
        const float2 e = *(const float2*)(emb + row * 50 + ps * 2);
        const int bk = ps * 4, slot = bk >> 4, within = bk & 15;
        *(u32*)(&Abuf[0][pm * ROWB + ((slot ^ (pm & 7)) << 4) + within]) =
            packh2(e.x, e.y);
    }
    __syncthreads();

    float cst[4] = {0.f, 0.f, 0.f, 0.f};
    float rm[4]  = {-3e38f, -3e38f, -3e38f, -3e38f};

    const int hd      = gg * 16 + l15;          // hidden dim owned by lane
    const int hslot   = (128 + hd * 2) >> 4;    // A-row slot of h[hd]
    const int hwithin = (hd * 2) & 15;

    // prefetch lanes: waves 8..15, first 400 of them
    const int tid2   = tid - 512;
    const bool pfthr = (tid2 >= 0) && (tid2 < 400);
    const int pm2 = pfthr ? (tid2 / 25) : 0;
    const int ps2 = pfthr ? (tid2 % 25) : 0;

    for (int s = 0; s < TT; ++s) {
        const int cur = s & 1;
        const int t   = rev ? (TT - 1 - s) : s;

        // prefetch next step's x row-pair (issued early, consumed after bar A)
        float2 e;
        const bool pf = pfthr && (s + 1 < TT);
        if (pf) {
            const int t1  = rev ? (TT - 2 - s) : (s + 1);
            const int row = idx16[pm2 * TT + t1];
            e = *(const float2*)(emb + row * 50 + ps2 * 2);
        }

        // ---- MFMA: 2 tiles x 6 K-steps
        const unsigned char* ab = &Abuf[cur][0];
        f32x4 a0 = {bias_v[0], bias_v[0], bias_v[0], bias_v[0]};
        f32x4 a1 = {bias_v[1], bias_v[1], bias_v[1], bias_v[1]};
#pragma unroll
        for (int kt = 0; kt < 6; ++kt) {
            const f16x8 af = *(const f16x8*)(
                ab + l15 * ROWB + ((((kt << 2) | c4) ^ (l15 & 7)) << 4));
            a0 = __builtin_amdgcn_mfma_f32_16x16x32_f16(af, w[kt][0], a0, 0, 0, 0);
            a1 = __builtin_amdgcn_mfma_f32_16x16x32_f16(af, w[kt][1], a1, 0, 0, 0);
        }

        // ---- phase 1: wave-half-parallel gate nonlinearities
        float si[4], tg[4];
        if (hf) {
            // a0 = f, a1 = o
#pragma unroll
            for (int q = 0; q < 4; ++q) {
                const int m = c4 * 4 + q;
                sf_l[hd * 17 + m] = sigf(a0[q]);
                so_l[hd * 17 + m] = sigf(a1[q]);
            }
        } else {
            // a0 = i, a1 = g
#pragma unroll
            for (int q = 0; q < 4; ++q) {
                si[q] = sigf(a0[q]);
                tg[q] = tanhf_(a1[q]);
            }
        }
        __syncthreads();   // barrier A: sigma(f)/sigma(o) visible

        // ---- phase 2: c/h update (waves 0..7); x write (waves 8..15)
        unsigned char* nb = &Abuf[cur ^ 1][0];
        if (!hf) {
            const u32 mb = mbits[t];
#pragma unroll
            for (int q = 0; q < 4; ++q) {
                const int m = c4 * 4 + q;
                const float sfv = sf_l[hd * 17 + m];
                const float sov = so_l[hd * 17 + m];
                const float cc = sfv * cst[q] + si[q] * tg[q];
                cst[q] = cc;
                const float hh = sov * tanhf_(cc);
                const float pen = ((mb >> m) & 1u) ? 0.f : 1e8f;
                rm[q] = fmaxf(rm[q], hh - pen);
                *(u16*)(nb + m * ROWB + ((hslot ^ (m & 7)) << 4) + hwithin) =
                    f16bits(hh);
            }
        } else if (pf) {
            const int bk = ps2 * 4, slot = bk >> 4, within = bk & 15;
            *(u32*)(nb + pm2 * ROWB + ((slot ^ (pm2 & 7)) << 4) + within) =
                packh2(e.x, e.y);
        }
        __syncthreads();   // barrier B: h + x writes visible for next step
    }

    if (!hf) {
#pragma unroll
        for (int q = 0; q < 4; ++q) {
            const int bb = b0 + c4 * 4 + q;
            out[bb * 256 + d * 128 + hd] = rm[q];
        }
    }
}

extern "C" void kernel_launch(void* const* d_in, const int* in_sizes, int n_in,
                              void* d_out, int out_size, void* d_ws, size_t ws_size,
                              hipStream_t stream) {
    const int*   idx   = (const int*)d_in[0];
    const float* masks = (const float*)d_in[1];
    const float* emb   = (const float*)d_in[2];
    const float* Wih_f = (const float*)d_in[3];
    const float* Whh_f = (const float*)d_in[4];
    const float* bih_f = (const float*)d_in[5];
    const float* bhh_f = (const float*)d_in[6];
    const float* Wih_b = (const float*)d_in[7];
    const float* Whh_b = (const float*)d_in[8];
    const float* bih_b = (const float*)d_in[9];
    const float* bhh_b = (const float*)d_in[10];
    float* out = (float*)d_out;

    bilstm_mfma16_kernel<<<dim3(32), dim3(1024), 0, stream>>>(
        idx, masks, emb,
        Wih_f, Whh_f, bih_f, bhh_f,
        Wih_b, Whh_b, bih_b, bhh_b,
        out);
}

// Round 9
// 562.682 us; speedup vs baseline: 1.0953x; 1.0953x over previous
//
#include <hip/hip_runtime.h>
#include <hip/hip_fp16.h>

// Bidirectional char-LSTM + masked max-pool via MFMA, operand-swapped.
// 32 blocks = 2 dirs x 16 chain-groups; block runs 16 chains (shared weights),
// T=512 steps, 8 waves.
// Per step: D'[512 gates][16 chains] = W[512][192] x H[192][16] via
// mfma_f32_16x16x32_f16 with W as the A-operand (static, in VGPRs: 24 f16x8
// frags/wave) and H as the B-operand from LDS.
// H layout = 6 chunks of 1KB (one per K-tile kt), fragment-ordered so lane l
// reads bytes [l*16,l*16+16) -> fully contiguous wave read, ZERO bank
// conflicts (R7/R8 lesson: row-major A-tile at stride 384B was ~8-way
// conflicted; 48KB/step of conflicted ds_read was the 2750cyc/step wall).
// Acc layout (row=gate, col=chain): lane (c4,l15) holds chain l15, gates
// wv*16+c4*4+q (+128k offsets) -> i,f,g,o same lane AND the 4 written h dims
// are consecutive -> one aligned ds_write_b64 per lane.
// K mapping: k<50 = x (prefetched from emb each step); 50..63 = zero pad;
// k>=64 = h[k-64]. One barrier per step.

#define TT 512
#define CH 16

typedef _Float16 f16;
typedef _Float16 f16x8 __attribute__((ext_vector_type(8)));
typedef float f32x4 __attribute__((ext_vector_type(4)));
typedef unsigned int u32;
typedef unsigned short u16;

static __device__ __forceinline__ u32 packh2(float lo, float hi) {
    union { struct { f16 x, y; } h; u32 u; } cv;
    cv.h.x = (f16)lo; cv.h.y = (f16)hi;
    return cv.u;
}
static __device__ __forceinline__ float fexp(float x) {
    return __builtin_amdgcn_exp2f(x * 1.44269504088896341f);
}
static __device__ __forceinline__ float frcp(float x) {
    return __builtin_amdgcn_rcpf(x);
}
static __device__ __forceinline__ float sigf(float x) {
    return frcp(1.f + fexp(-x));
}
static __device__ __forceinline__ float tanhf_(float x) {
    return 1.f - 2.f * frcp(fexp(2.f * x) + 1.f);
}

__global__ __attribute__((amdgpu_flat_work_group_size(512, 512),
                          amdgpu_waves_per_eu(2, 2)))
void bilstm_mfma_swap_kernel(const int* __restrict__ idx,
                             const float* __restrict__ masks,
                             const float* __restrict__ emb,
                             const float* __restrict__ Wih_f, const float* __restrict__ Whh_f,
                             const float* __restrict__ bih_f, const float* __restrict__ bhh_f,
                             const float* __restrict__ Wih_b, const float* __restrict__ Whh_b,
                             const float* __restrict__ bih_b, const float* __restrict__ bhh_b,
                             float* __restrict__ out)
{
    // Hbuf[buf][kt][c4k][chain][j]: 2 x 6 x 1KB. Value at (kt,c4k,chain,j) is
    // H[k = kt*32 + c4k*8 + j][chain] (fp16).
    __shared__ __align__(16) unsigned char Hbuf[2][6 * 1024];  // 12 KB
    __shared__ u16 idx16[CH * TT];                             // 16 KB
    __shared__ u32 mbits[TT];                                  // 2 KB

    const int tid  = threadIdx.x;
    const int lane = tid & 63;
    const int wv   = tid >> 6;        // wave 0..7
    const int l15  = lane & 15;       // chain owned by lane (acc col)
    const int c4   = lane >> 4;       // 0..3
    const int d    = blockIdx.x >> 4; // 0 fwd, 1 bwd
    const int g    = blockIdx.x & 15;
    const int b0   = g * CH;
    const int rev  = d;

    const float* Wih = d ? Wih_b : Wih_f;
    const float* Whh = d ? Whh_b : Whh_f;
    const float* bih = d ? bih_b : bih_f;
    const float* bhh = d ? bhh_b : bhh_f;

    // ---- init: idx (u16), mask bitmasks, zero H buffers
    for (int i = tid; i < CH * TT; i += 512) {
        const int m = i >> 9, t = i & 511;
        idx16[i] = (u16)idx[(b0 + m) * TT + t];
    }
    if (tid < TT) {
        u32 mb = 0;
        for (int m = 0; m < CH; ++m)
            mb |= (masks[(b0 + m) * TT + tid] != 0.f ? 1u : 0u) << m;
        mbits[tid] = mb;
    }
    for (int i = tid; i < 2 * 6 * 1024 / 4; i += 512)
        ((u32*)Hbuf)[i] = 0u;

    // ---- W fragments (A-operand) in VGPRs: w[kt][gt], gt = i/f/g/o.
    // Lane provides A[row = gate][k]: gate n = (wv + gt*8)*16 + l15,
    // k = kt*32 + c4*8 + j, j = 0..7.
    f16x8 w[6][4];
    f32x4 bias4[4];
#pragma unroll
    for (int gt = 0; gt < 4; ++gt) {
        const int n = (wv + gt * 8) * 16 + l15;
        {   // bias for acc rows: gates (wv+gt*8)*16 + c4*4 + q, q=0..3
            const int nb_ = (wv + gt * 8) * 16 + c4 * 4;
            const float4 bi = *(const float4*)(bih + nb_);
            const float4 bh = *(const float4*)(bhh + nb_);
            bias4[gt][0] = bi.x + bh.x; bias4[gt][1] = bi.y + bh.y;
            bias4[gt][2] = bi.z + bh.z; bias4[gt][3] = bi.w + bh.w;
        }
        // kt = 0: k = c4*8 + j (< 32 < 50) -> Wih (float2 loads: 8B aligned)
#pragma unroll
        for (int jj = 0; jj < 4; ++jj) {
            const float2 e = *(const float2*)(Wih + n * 50 + c4 * 8 + jj * 2);
            w[0][gt][2 * jj]     = (f16)e.x;
            w[0][gt][2 * jj + 1] = (f16)e.y;
        }
        // kt = 1: k = 32 + c4*8 + j, real iff k < 50
#pragma unroll
        for (int j = 0; j < 8; ++j) {
            const int k = 32 + c4 * 8 + j;
            float v = 0.f;
            if (k < 50) v = Wih[n * 50 + k];
            w[1][gt][j] = (f16)v;
        }
        // kt = 2..5: k >= 64 -> Whh[n][k-64] (16B aligned float4 x2)
#pragma unroll
        for (int kt = 2; kt < 6; ++kt) {
            const int kh = (kt - 2) * 32 + c4 * 8;
            const float4 e0 = *(const float4*)(Whh + n * 128 + kh);
            const float4 e1 = *(const float4*)(Whh + n * 128 + kh + 4);
            w[kt][gt][0] = (f16)e0.x; w[kt][gt][1] = (f16)e0.y;
            w[kt][gt][2] = (f16)e0.z; w[kt][gt][3] = (f16)e0.w;
            w[kt][gt][4] = (f16)e1.x; w[kt][gt][5] = (f16)e1.y;
            w[kt][gt][6] = (f16)e1.z; w[kt][gt][7] = (f16)e1.w;
        }
    }

    __syncthreads();   // idx16/mbits/Hbuf-zero visible before x store

    // ---- x for step 0: threads 0..399 (25 per chain, 2 halves each)
    if (tid < 400) {
        const int pm = tid / 25, ps = tid % 25;
        const int t0  = rev ? (TT - 1) : 0;
        const int row = idx16[pm * TT + t0];
        const float2 e = *(const float2*)(emb + row * 50 + ps * 2);
        const int k0 = 2 * ps;
        const int kt = k0 >> 5, c4k = (k0 >> 3) & 3, j = k0 & 7;
        *(u32*)(&Hbuf[0][(kt << 10) + ((c4k * 16 + pm) << 4) + (j << 1)]) =
            packh2(e.x, e.y);
    }
    __syncthreads();

    float cst[4] = {0.f, 0.f, 0.f, 0.f};
    float rm[4]  = {-3e38f, -3e38f, -3e38f, -3e38f};

    // h-writeback address components (lane owns chain l15, dims
    // hd_q = wv*16 + c4*4 + q -> k = 64 + hd_q):
    const int wb_kt  = 2 + (wv >> 1);
    const int wb_c4k = (wv * 2 + (c4 >> 1)) & 3;
    const int wb_off = (wb_kt << 10) + ((wb_c4k * 16 + l15) << 4) + ((c4 & 1) << 3);

    for (int s = 0; s < TT; ++s) {
        const int cur = s & 1;
        const int t   = rev ? (TT - 1 - s) : s;

        // prefetch next step's x row-pair (hidden under MFMA)
        float2 e;
        int pk0 = 0;
        const bool pf = (tid < 400) && (s + 1 < TT);
        const int pm = tid / 25, ps = tid % 25;
        if (pf) {
            const int t1  = rev ? (TT - 2 - s) : (s + 1);
            const int row = idx16[pm * TT + t1];
            e = *(const float2*)(emb + row * 50 + ps * 2);
            pk0 = 2 * ps;
        }

        // ---- MFMA: 4 gate tiles x 6 K-steps; B-frag = contiguous 16B/lane
        const unsigned char* hb = &Hbuf[cur][0];
        f32x4 ai = bias4[0], af = bias4[1], ag = bias4[2], ao = bias4[3];
#pragma unroll
        for (int kt = 0; kt < 6; ++kt) {
            const f16x8 bf = *(const f16x8*)(hb + (kt << 10) + (lane << 4));
            ai = __builtin_amdgcn_mfma_f32_16x16x32_f16(w[kt][0], bf, ai, 0, 0, 0);
            af = __builtin_amdgcn_mfma_f32_16x16x32_f16(w[kt][1], bf, af, 0, 0, 0);
            ag = __builtin_amdgcn_mfma_f32_16x16x32_f16(w[kt][2], bf, ag, 0, 0, 0);
            ao = __builtin_amdgcn_mfma_f32_16x16x32_f16(w[kt][3], bf, ao, 0, 0, 0);
        }

        // ---- in-lane LSTM update: chain l15, dims wv*16 + c4*4 + q
        const float pen = ((mbits[t] >> l15) & 1u) ? 0.f : 1e8f;
        unsigned char* nb = &Hbuf[cur ^ 1][0];
        float hh[4];
#pragma unroll
        for (int q = 0; q < 4; ++q) {
            const float cc = sigf(af[q]) * cst[q] + sigf(ai[q]) * tanhf_(ag[q]);
            cst[q] = cc;
            hh[q] = sigf(ao[q]) * tanhf_(cc);
            rm[q] = fmaxf(rm[q], hh[q] - pen);
        }
        {   // one aligned 8B write: 4 consecutive h dims of chain l15
            uint2 pk;
            pk.x = packh2(hh[0], hh[1]);
            pk.y = packh2(hh[2], hh[3]);
            *(uint2*)(nb + wb_off) = pk;
        }
        if (pf) {
            const int kt = pk0 >> 5, c4k = (pk0 >> 3) & 3, j = pk0 & 7;
            *(u32*)(nb + (kt << 10) + ((c4k * 16 + pm) << 4) + (j << 1)) =
                packh2(e.x, e.y);
        }
        __syncthreads();
    }

    // ---- output: chain b0+l15, dims wv*16 + c4*4 + 0..3 (16B aligned)
    {
        float4 o4 = make_float4(rm[0], rm[1], rm[2], rm[3]);
        *(float4*)(out + (b0 + l15) * 256 + d * 128 + wv * 16 + c4 * 4) = o4;
    }
}

extern "C" void kernel_launch(void* const* d_in, const int* in_sizes, int n_in,
                              void* d_out, int out_size, void* d_ws, size_t ws_size,
                              hipStream_t stream) {
    const int*   idx   = (const int*)d_in[0];
    const float* masks = (const float*)d_in[1];
    const float* emb   = (const float*)d_in[2];
    const float* Wih_f = (const float*)d_in[3];
    const float* Whh_f = (const float*)d_in[4];
    const float* bih_f = (const float*)d_in[5];
    const float* bhh_f = (const float*)d_in[6];
    const float* Wih_b = (const float*)d_in[7];
    const float* Whh_b = (const float*)d_in[8];
    const float* bih_b = (const float*)d_in[9];
    const float* bhh_b = (const float*)d_in[10];
    float* out = (float*)d_out;

    bilstm_mfma_swap_kernel<<<dim3(32), dim3(512), 0, stream>>>(
        idx, masks, emb,
        Wih_f, Whh_f, bih_f, bhh_f,
        Wih_b, Whh_b, bih_b, bhh_b,
        out);
}

// Round 10
// 438.196 us; speedup vs baseline: 1.4065x; 1.2841x over previous
//
#include <hip/hip_runtime.h>
#include <hip/hip_fp16.h>

// Bidirectional char-LSTM + masked max-pool via MFMA, operand-swapped,
// chain-split CH=8 with duplicated B-columns.
// 64 blocks = 2 dirs x 32 chain-groups of 8; T=512 steps, 8 waves.
// R9 analysis: the wall is transcendental issue (~16cyc/wave64, 20 nonlin/lane
// = 640cyc/wave/step) on only 32 CUs. Fix: halve chains/block -> 64 CUs, and
// duplicate chains into B cols 8-15 so D cols 8-15 replicate 0-7: lanes
// l15>=8 process the OTHER q-pair (dims +2,+3) of chain l15&7 instead of
// idling -> activation per lane halves (10 nonlin), no cross-lane exchange.
// Per step: D'[512 gates][16 cols(8 chains x2)] = W[512][192] x H[192][16]
// via mfma_f32_16x16x32_f16; W static in VGPRs (24 f16x8/wave); H in LDS,
// fragment-ordered (lane l reads bytes [l*16,l*16+16) -> conflict-free).
// h-writeback: one packed u32 (2 dims) to both column copies. One barrier/step.

#define TT 512
#define CH 8

typedef _Float16 f16;
typedef _Float16 f16x8 __attribute__((ext_vector_type(8)));
typedef float f32x4 __attribute__((ext_vector_type(4)));
typedef unsigned int u32;
typedef unsigned short u16;

static __device__ __forceinline__ u32 packh2(float lo, float hi) {
    union { struct { f16 x, y; } h; u32 u; } cv;
    cv.h.x = (f16)lo; cv.h.y = (f16)hi;
    return cv.u;
}
static __device__ __forceinline__ float fexp(float x) {
    return __builtin_amdgcn_exp2f(x * 1.44269504088896341f);
}
static __device__ __forceinline__ float frcp(float x) {
    return __builtin_amdgcn_rcpf(x);
}
static __device__ __forceinline__ float sigf(float x) {
    return frcp(1.f + fexp(-x));
}
static __device__ __forceinline__ float tanhf_(float x) {
    return 1.f - 2.f * frcp(fexp(2.f * x) + 1.f);
}

__global__ __attribute__((amdgpu_flat_work_group_size(512, 512),
                          amdgpu_waves_per_eu(2, 2)))
void bilstm_mfma_ch8_kernel(const int* __restrict__ idx,
                            const float* __restrict__ masks,
                            const float* __restrict__ emb,
                            const float* __restrict__ Wih_f, const float* __restrict__ Whh_f,
                            const float* __restrict__ bih_f, const float* __restrict__ bhh_f,
                            const float* __restrict__ Wih_b, const float* __restrict__ Whh_b,
                            const float* __restrict__ bih_b, const float* __restrict__ bhh_b,
                            float* __restrict__ out)
{
    // Hbuf[buf][kt][c4k][col][j]: value = H[k = kt*32 + c4k*8 + j][col] fp16,
    // col = chain | chain+8 (duplicated).
    __shared__ __align__(16) unsigned char Hbuf[2][6 * 1024];  // 12 KB
    __shared__ u16 idx16[CH * TT];                             // 8 KB
    __shared__ u32 mbits[TT];                                  // 2 KB

    const int tid  = threadIdx.x;
    const int lane = tid & 63;
    const int wv   = tid >> 6;        // wave 0..7
    const int l15  = lane & 15;       // acc col
    const int c4   = lane >> 4;       // 0..3 (acc row group)
    const int d    = blockIdx.x & 1;  // 0 fwd, 1 bwd
    const int g    = blockIdx.x >> 1; // 0..31
    const int b0   = g * CH;
    const int rev  = d;

    const int qsel  = l15 >> 3;       // 0: dims +0,+1 ; 1: dims +2,+3
    const int chain = l15 & 7;

    const float* Wih = d ? Wih_b : Wih_f;
    const float* Whh = d ? Whh_b : Whh_f;
    const float* bih = d ? bih_b : bih_f;
    const float* bhh = d ? bhh_b : bhh_f;

    // ---- init: idx (u16), mask bitmasks, zero H buffers
    for (int i = tid; i < CH * TT; i += 512) {
        const int m = i >> 9, t = i & 511;
        idx16[i] = (u16)idx[(b0 + m) * TT + t];
    }
    if (tid < TT) {
        u32 mb = 0;
        for (int m = 0; m < CH; ++m)
            mb |= (masks[(b0 + m) * TT + tid] != 0.f ? 1u : 0u) << m;
        mbits[tid] = mb;
    }
    for (int i = tid; i < 2 * 6 * 1024 / 4; i += 512)
        ((u32*)Hbuf)[i] = 0u;

    // ---- W fragments (A-operand) in VGPRs: w[kt][gt], gt = i/f/g/o.
    // Lane provides A[row = gate][k]: gate n = (wv + gt*8)*16 + l15,
    // k = kt*32 + c4*8 + j, j = 0..7.
    f16x8 w[6][4];
    f32x4 bias4[4];
#pragma unroll
    for (int gt = 0; gt < 4; ++gt) {
        const int n = (wv + gt * 8) * 16 + l15;
        {   // bias for acc rows: gates (wv+gt*8)*16 + c4*4 + q, q=0..3
            const int nb_ = (wv + gt * 8) * 16 + c4 * 4;
            const float4 bi = *(const float4*)(bih + nb_);
            const float4 bh = *(const float4*)(bhh + nb_);
            bias4[gt][0] = bi.x + bh.x; bias4[gt][1] = bi.y + bh.y;
            bias4[gt][2] = bi.z + bh.z; bias4[gt][3] = bi.w + bh.w;
        }
        // kt = 0: k = c4*8 + j (< 32 < 50) -> Wih (float2 loads: 8B aligned)
#pragma unroll
        for (int jj = 0; jj < 4; ++jj) {
            const float2 e = *(const float2*)(Wih + n * 50 + c4 * 8 + jj * 2);
            w[0][gt][2 * jj]     = (f16)e.x;
            w[0][gt][2 * jj + 1] = (f16)e.y;
        }
        // kt = 1: k = 32 + c4*8 + j, real iff k < 50
#pragma unroll
        for (int j = 0; j < 8; ++j) {
            const int k = 32 + c4 * 8 + j;
            float v = 0.f;
            if (k < 50) v = Wih[n * 50 + k];
            w[1][gt][j] = (f16)v;
        }
        // kt = 2..5: k >= 64 -> Whh[n][k-64] (16B aligned float4 x2)
#pragma unroll
        for (int kt = 2; kt < 6; ++kt) {
            const int kh = (kt - 2) * 32 + c4 * 8;
            const float4 e0 = *(const float4*)(Whh + n * 128 + kh);
            const float4 e1 = *(const float4*)(Whh + n * 128 + kh + 4);
            w[kt][gt][0] = (f16)e0.x; w[kt][gt][1] = (f16)e0.y;
            w[kt][gt][2] = (f16)e0.z; w[kt][gt][3] = (f16)e0.w;
            w[kt][gt][4] = (f16)e1.x; w[kt][gt][5] = (f16)e1.y;
            w[kt][gt][6] = (f16)e1.z; w[kt][gt][7] = (f16)e1.w;
        }
    }

    __syncthreads();   // idx16/mbits/Hbuf-zero visible before x store

    // ---- x for step 0: threads 0..399, col pm = 0..15 (chain pm&7 dup'd)
    if (tid < 400) {
        const int pm = tid / 25, ps = tid % 25;
        const int t0  = rev ? (TT - 1) : 0;
        const int row = idx16[(pm & 7) * TT + t0];
        const float2 e = *(const float2*)(emb + row * 50 + ps * 2);
        const int k0 = 2 * ps;
        const int kt = k0 >> 5, c4k = (k0 >> 3) & 3, j = k0 & 7;
        *(u32*)(&Hbuf[0][(kt << 10) + ((c4k * 16 + pm) << 4) + (j << 1)]) =
            packh2(e.x, e.y);
    }
    __syncthreads();

    float cst0 = 0.f, cst1 = 0.f;
    float rm0 = -3e38f, rm1 = -3e38f;

    // h-writeback: lane owns chain, dims hd0 = wv*16 + c4*4 + 2*qsel, hd0+1
    const int hd0   = wv * 16 + c4 * 4 + 2 * qsel;
    const int k0h   = 64 + hd0;
    const int wb_kt  = k0h >> 5;
    const int wb_c4k = (k0h >> 3) & 3;
    const int wb_j   = k0h & 7;
    const int wb_off = (wb_kt << 10) + ((wb_c4k * 16 + chain) << 4) + (wb_j << 1);

    for (int s = 0; s < TT; ++s) {
        const int cur = s & 1;
        const int t   = rev ? (TT - 1 - s) : s;

        // prefetch next step's x row-pair (hidden under MFMA)
        float2 e;
        int pk0 = 0;
        const bool pf = (tid < 400) && (s + 1 < TT);
        const int pm = tid / 25, ps = tid % 25;
        if (pf) {
            const int t1  = rev ? (TT - 2 - s) : (s + 1);
            const int row = idx16[(pm & 7) * TT + t1];
            e = *(const float2*)(emb + row * 50 + ps * 2);
            pk0 = 2 * ps;
        }

        // ---- MFMA: 4 gate tiles x 6 K-steps; B-frag = contiguous 16B/lane
        const unsigned char* hb = &Hbuf[cur][0];
        f32x4 ai = bias4[0], af = bias4[1], ag = bias4[2], ao = bias4[3];
#pragma unroll
        for (int kt = 0; kt < 6; ++kt) {
            const f16x8 bf = *(const f16x8*)(hb + (kt << 10) + (lane << 4));
            ai = __builtin_amdgcn_mfma_f32_16x16x32_f16(w[kt][0], bf, ai, 0, 0, 0);
            af = __builtin_amdgcn_mfma_f32_16x16x32_f16(w[kt][1], bf, af, 0, 0, 0);
            ag = __builtin_amdgcn_mfma_f32_16x16x32_f16(w[kt][2], bf, ag, 0, 0, 0);
            ao = __builtin_amdgcn_mfma_f32_16x16x32_f16(w[kt][3], bf, ao, 0, 0, 0);
        }

        // ---- q-pair select (cols duplicated -> both lane halves valid)
        const float iv0 = qsel ? ai[2] : ai[0], iv1 = qsel ? ai[3] : ai[1];
        const float fv0 = qsel ? af[2] : af[0], fv1 = qsel ? af[3] : af[1];
        const float gv0 = qsel ? ag[2] : ag[0], gv1 = qsel ? ag[3] : ag[1];
        const float ov0 = qsel ? ao[2] : ao[0], ov1 = qsel ? ao[3] : ao[1];

        // ---- in-lane LSTM update: chain, dims hd0, hd0+1
        const float pen = ((mbits[t] >> chain) & 1u) ? 0.f : 1e8f;
        unsigned char* nb = &Hbuf[cur ^ 1][0];

        const float cc0 = sigf(fv0) * cst0 + sigf(iv0) * tanhf_(gv0);
        const float cc1 = sigf(fv1) * cst1 + sigf(iv1) * tanhf_(gv1);
        cst0 = cc0; cst1 = cc1;
        const float hh0 = sigf(ov0) * tanhf_(cc0);
        const float hh1 = sigf(ov1) * tanhf_(cc1);
        rm0 = fmaxf(rm0, hh0 - pen);
        rm1 = fmaxf(rm1, hh1 - pen);

        {   // packed 2-dim write to both column copies
            const u32 pk = packh2(hh0, hh1);
            *(u32*)(nb + wb_off)       = pk;
            *(u32*)(nb + wb_off + 128) = pk;   // col chain+8
        }
        if (pf) {
            const int kt = pk0 >> 5, c4k = (pk0 >> 3) & 3, j = pk0 & 7;
            *(u32*)(nb + (kt << 10) + ((c4k * 16 + pm) << 4) + (j << 1)) =
                packh2(e.x, e.y);
        }
        __syncthreads();
    }

    // ---- output: chain b0+chain, dims hd0, hd0+1 (8B aligned)
    {
        float2 o2; o2.x = rm0; o2.y = rm1;
        *(float2*)(out + (b0 + chain) * 256 + d * 128 + hd0) = o2;
    }
}

extern "C" void kernel_launch(void* const* d_in, const int* in_sizes, int n_in,
                              void* d_out, int out_size, void* d_ws, size_t ws_size,
                              hipStream_t stream) {
    const int*   idx   = (const int*)d_in[0];
    const float* masks = (const float*)d_in[1];
    const float* emb   = (const float*)d_in[2];
    const float* Wih_f = (const float*)d_in[3];
    const float* Whh_f = (const float*)d_in[4];
    const float* bih_f = (const float*)d_in[5];
    const float* bhh_f = (const float*)d_in[6];
    const float* Wih_b = (const float*)d_in[7];
    const float* Whh_b = (const float*)d_in[8];
    const float* bih_b = (const float*)d_in[9];
    const float* bhh_b = (const float*)d_in[10];
    float* out = (float*)d_out;

    bilstm_mfma_ch8_kernel<<<dim3(64), dim3(512), 0, stream>>>(
        idx, masks, emb,
        Wih_f, Whh_f, bih_f, bhh_f,
        Wih_b, Whh_b, bih_b, bhh_b,
        out);
}

// Round 11
// 397.614 us; speedup vs baseline: 1.5501x; 1.1021x over previous
//
#include <hip/hip_runtime.h>
#include <hip/hip_fp16.h>

// Bidirectional char-LSTM + masked max-pool via MFMA, operand-swapped,
// chain-split CH=4 with 4x-duplicated B-columns.
// 128 blocks = 2 dirs x 64 chain-groups of 4; T=512 steps, 8 waves.
// Ladder: R9 (CH=16) 566us -> R10 (CH=8, 2x dup) 438us: the wall is
// transcendental issue spread over too few CUs. CH=4 puts the fixed trans
// work on 128 CUs and leaves each lane ONE (chain,dim) task: 5 nonlins =
// 10 trans/step (R10: 20), q-row selected by qsel = l15>>2 via nested
// ternaries (compile-time vector indices -> no scratch).
// Per step: D'[512 gates][16 cols(4 chains x4)] = W[512][192] x H[192][16]
// via mfma_f32_16x16x32_f16; W static in VGPRs (24 f16x8/wave); H in LDS,
// fragment-ordered (lane l reads bytes [l*16,l*16+16) -> conflict-free).
// h-writeback: one u16 to each of 4 column copies. One barrier per step.

#define TT 512
#define CH 4

typedef _Float16 f16;
typedef _Float16 f16x8 __attribute__((ext_vector_type(8)));
typedef float f32x4 __attribute__((ext_vector_type(4)));
typedef unsigned int u32;
typedef unsigned short u16;

static __device__ __forceinline__ u32 packh2(float lo, float hi) {
    union { struct { f16 x, y; } h; u32 u; } cv;
    cv.h.x = (f16)lo; cv.h.y = (f16)hi;
    return cv.u;
}
static __device__ __forceinline__ u16 f16bits(float v) {
    union { f16 h; u16 u; } cv; cv.h = (f16)v; return cv.u;
}
static __device__ __forceinline__ float fexp(float x) {
    return __builtin_amdgcn_exp2f(x * 1.44269504088896341f);
}
static __device__ __forceinline__ float frcp(float x) {
    return __builtin_amdgcn_rcpf(x);
}
static __device__ __forceinline__ float sigf(float x) {
    return frcp(1.f + fexp(-x));
}
static __device__ __forceinline__ float tanhf_(float x) {
    return 1.f - 2.f * frcp(fexp(2.f * x) + 1.f);
}
static __device__ __forceinline__ float sel4(f32x4 v, int q) {
    // q in 0..3, compile-time indices in each arm (rule #20: no dyn index)
    return (q & 2) ? ((q & 1) ? v[3] : v[2]) : ((q & 1) ? v[1] : v[0]);
}

__global__ __attribute__((amdgpu_flat_work_group_size(512, 512),
                          amdgpu_waves_per_eu(2, 2)))
void bilstm_mfma_ch4_kernel(const int* __restrict__ idx,
                            const float* __restrict__ masks,
                            const float* __restrict__ emb,
                            const float* __restrict__ Wih_f, const float* __restrict__ Whh_f,
                            const float* __restrict__ bih_f, const float* __restrict__ bhh_f,
                            const float* __restrict__ Wih_b, const float* __restrict__ Whh_b,
                            const float* __restrict__ bih_b, const float* __restrict__ bhh_b,
                            float* __restrict__ out)
{
    // Hbuf[buf][kt][c4k][col][j]: value = H[k = kt*32 + c4k*8 + j][col] fp16,
    // col = chain + 4*copy (4 copies).
    __shared__ __align__(16) unsigned char Hbuf[2][6 * 1024];  // 12 KB
    __shared__ u16 idx16[CH * TT];                             // 4 KB
    __shared__ u32 mbits[TT];                                  // 2 KB

    const int tid  = threadIdx.x;
    const int lane = tid & 63;
    const int wv   = tid >> 6;        // wave 0..7
    const int l15  = lane & 15;       // acc col
    const int c4   = lane >> 4;       // 0..3 (acc row group)
    const int d    = blockIdx.x & 1;  // 0 fwd, 1 bwd
    const int g    = blockIdx.x >> 1; // 0..63
    const int b0   = g * CH;
    const int rev  = d;

    const int qsel  = l15 >> 2;       // 0..3: which acc row q this lane owns
    const int chain = l15 & 3;

    const float* Wih = d ? Wih_b : Wih_f;
    const float* Whh = d ? Whh_b : Whh_f;
    const float* bih = d ? bih_b : bih_f;
    const float* bhh = d ? bhh_b : bhh_f;

    // ---- init: idx (u16), mask bitmasks, zero H buffers
    for (int i = tid; i < CH * TT; i += 512) {
        const int m = i >> 9, t = i & 511;
        idx16[i] = (u16)idx[(b0 + m) * TT + t];
    }
    if (tid < TT) {
        u32 mb = 0;
        for (int m = 0; m < CH; ++m)
            mb |= (masks[(b0 + m) * TT + tid] != 0.f ? 1u : 0u) << m;
        mbits[tid] = mb;
    }
    for (int i = tid; i < 2 * 6 * 1024 / 4; i += 512)
        ((u32*)Hbuf)[i] = 0u;

    // ---- W fragments (A-operand) in VGPRs: w[kt][gt], gt = i/f/g/o.
    // Lane provides A[row = gate][k]: gate n = (wv + gt*8)*16 + l15,
    // k = kt*32 + c4*8 + j, j = 0..7.
    f16x8 w[6][4];
    f32x4 bias4[4];
#pragma unroll
    for (int gt = 0; gt < 4; ++gt) {
        const int n = (wv + gt * 8) * 16 + l15;
        {   // bias for acc rows: gates (wv+gt*8)*16 + c4*4 + q, q=0..3
            const int nb_ = (wv + gt * 8) * 16 + c4 * 4;
            const float4 bi = *(const float4*)(bih + nb_);
            const float4 bh = *(const float4*)(bhh + nb_);
            bias4[gt][0] = bi.x + bh.x; bias4[gt][1] = bi.y + bh.y;
            bias4[gt][2] = bi.z + bh.z; bias4[gt][3] = bi.w + bh.w;
        }
        // kt = 0: k = c4*8 + j (< 32 < 50) -> Wih (float2 loads: 8B aligned)
#pragma unroll
        for (int jj = 0; jj < 4; ++jj) {
            const float2 e = *(const float2*)(Wih + n * 50 + c4 * 8 + jj * 2);
            w[0][gt][2 * jj]     = (f16)e.x;
            w[0][gt][2 * jj + 1] = (f16)e.y;
        }
        // kt = 1: k = 32 + c4*8 + j, real iff k < 50
#pragma unroll
        for (int j = 0; j < 8; ++j) {
            const int k = 32 + c4 * 8 + j;
            float v = 0.f;
            if (k < 50) v = Wih[n * 50 + k];
            w[1][gt][j] = (f16)v;
        }
        // kt = 2..5: k >= 64 -> Whh[n][k-64] (16B aligned float4 x2)
#pragma unroll
        for (int kt = 2; kt < 6; ++kt) {
            const int kh = (kt - 2) * 32 + c4 * 8;
            const float4 e0 = *(const float4*)(Whh + n * 128 + kh);
            const float4 e1 = *(const float4*)(Whh + n * 128 + kh + 4);
            w[kt][gt][0] = (f16)e0.x; w[kt][gt][1] = (f16)e0.y;
            w[kt][gt][2] = (f16)e0.z; w[kt][gt][3] = (f16)e0.w;
            w[kt][gt][4] = (f16)e1.x; w[kt][gt][5] = (f16)e1.y;
            w[kt][gt][6] = (f16)e1.z; w[kt][gt][7] = (f16)e1.w;
        }
    }

    __syncthreads();   // idx16/mbits/Hbuf-zero visible before x store

    // ---- x for step 0: threads 0..399, col pm = 0..15 (chain pm&3, 4 copies)
    if (tid < 400) {
        const int pm = tid / 25, ps = tid % 25;
        const int t0  = rev ? (TT - 1) : 0;
        const int row = idx16[(pm & 3) * TT + t0];
        const float2 e = *(const float2*)(emb + row * 50 + ps * 2);
        const int k0 = 2 * ps;
        const int kt = k0 >> 5, c4k = (k0 >> 3) & 3, j = k0 & 7;
        *(u32*)(&Hbuf[0][(kt << 10) + ((c4k * 16 + pm) << 4) + (j << 1)]) =
            packh2(e.x, e.y);
    }
    __syncthreads();

    float cst0 = 0.f, rm0 = -3e38f;

    // h-writeback: lane owns chain, single dim hd = wv*16 + c4*4 + qsel
    const int hd    = wv * 16 + c4 * 4 + qsel;
    const int k0h   = 64 + hd;
    const int wb_kt  = k0h >> 5;
    const int wb_c4k = (k0h >> 3) & 3;
    const int wb_j   = k0h & 7;
    const int wb_off = (wb_kt << 10) + ((wb_c4k * 16 + chain) << 4) + (wb_j << 1);

    for (int s = 0; s < TT; ++s) {
        const int cur = s & 1;
        const int t   = rev ? (TT - 1 - s) : s;

        // prefetch next step's x row-pair (hidden under MFMA)
        float2 e;
        int pk0 = 0;
        const bool pf = (tid < 400) && (s + 1 < TT);
        const int pm = tid / 25, ps = tid % 25;
        if (pf) {
            const int t1  = rev ? (TT - 2 - s) : (s + 1);
            const int row = idx16[(pm & 3) * TT + t1];
            e = *(const float2*)(emb + row * 50 + ps * 2);
            pk0 = 2 * ps;
        }

        // ---- MFMA: 4 gate tiles x 6 K-steps; B-frag = contiguous 16B/lane
        const unsigned char* hb = &Hbuf[cur][0];
        f32x4 ai = bias4[0], af = bias4[1], ag = bias4[2], ao = bias4[3];
#pragma unroll
        for (int kt = 0; kt < 6; ++kt) {
            const f16x8 bf = *(const f16x8*)(hb + (kt << 10) + (lane << 4));
            ai = __builtin_amdgcn_mfma_f32_16x16x32_f16(w[kt][0], bf, ai, 0, 0, 0);
            af = __builtin_amdgcn_mfma_f32_16x16x32_f16(w[kt][1], bf, af, 0, 0, 0);
            ag = __builtin_amdgcn_mfma_f32_16x16x32_f16(w[kt][2], bf, ag, 0, 0, 0);
            ao = __builtin_amdgcn_mfma_f32_16x16x32_f16(w[kt][3], bf, ao, 0, 0, 0);
        }

        // ---- q-row select (cols 4x duplicated -> all lane quarters valid)
        const float iv = sel4(ai, qsel);
        const float fv = sel4(af, qsel);
        const float gv = sel4(ag, qsel);
        const float ov = sel4(ao, qsel);

        // ---- in-lane LSTM update: chain, single dim hd
        const float pen = ((mbits[t] >> chain) & 1u) ? 0.f : 1e8f;
        unsigned char* nb = &Hbuf[cur ^ 1][0];

        const float cc = sigf(fv) * cst0 + sigf(iv) * tanhf_(gv);
        cst0 = cc;
        const float hh = sigf(ov) * tanhf_(cc);
        rm0 = fmaxf(rm0, hh - pen);

        {   // u16 write to the 4 column copies (cols chain + {0,4,8,12})
            const u16 pk = f16bits(hh);
            *(u16*)(nb + wb_off)       = pk;
            *(u16*)(nb + wb_off + 64)  = pk;
            *(u16*)(nb + wb_off + 128) = pk;
            *(u16*)(nb + wb_off + 192) = pk;
        }
        if (pf) {
            const int kt = pk0 >> 5, c4k = (pk0 >> 3) & 3, j = pk0 & 7;
            *(u32*)(nb + (kt << 10) + ((c4k * 16 + pm) << 4) + (j << 1)) =
                packh2(e.x, e.y);
        }
        __syncthreads();
    }

    // ---- output: chain b0+chain, dim hd (scalar f32)
    out[(b0 + chain) * 256 + d * 128 + hd] = rm0;
}

extern "C" void kernel_launch(void* const* d_in, const int* in_sizes, int n_in,
                              void* d_out, int out_size, void* d_ws, size_t ws_size,
                              hipStream_t stream) {
    const int*   idx   = (const int*)d_in[0];
    const float* masks = (const float*)d_in[1];
    const float* emb   = (const float*)d_in[2];
    const float* Wih_f = (const float*)d_in[3];
    const float* Whh_f = (const float*)d_in[4];
    const float* bih_f = (const float*)d_in[5];
    const float* bhh_f = (const float*)d_in[6];
    const float* Wih_b = (const float*)d_in[7];
    const float* Whh_b = (const float*)d_in[8];
    const float* bih_b = (const float*)d_in[9];
    const float* bhh_b = (const float*)d_in[10];
    float* out = (float*)d_out;

    bilstm_mfma_ch4_kernel<<<dim3(128), dim3(512), 0, stream>>>(
        idx, masks, emb,
        Wih_f, Whh_f, bih_f, bhh_f,
        Wih_b, Whh_b, bih_b, bhh_b,
        out);
}